// Round 12
// baseline (73.217 us; speedup 1.0000x reference)
//
#include <hip/hip_runtime.h>

typedef float v2f __attribute__((ext_vector_type(2)));
typedef __fp16 h2 __attribute__((ext_vector_type(2)));
typedef __fp16 h8 __attribute__((ext_vector_type(8)));

#define B_ 64
#define T_ 2048
#define D_ 512
#define K_ 8
#define THREADS 256
#define TILE_R 32
#define XPITCH 520   // f16 pitch: 512 + 8 pad
#define LGPITCH 10
#define APITCH 12
#define LOG2E 1.44269504088896340736f

__device__ __forceinline__ float dev_exp2(float v) { return __builtin_amdgcn_exp2f(v); }
__device__ __forceinline__ h2 pack2(float a, float b) { return __builtin_amdgcn_cvt_pkrtz(a, b); }

__device__ __forceinline__ float fdot2(h2 a, h2 b, float c) {
#if __has_builtin(__builtin_amdgcn_fdot2)
  return __builtin_amdgcn_fdot2(a, b, c, false);
#else
  return c + (float)a[0] * (float)b[0] + (float)a[1] * (float)b[1];
#endif
}

// Kernel 1 (round 12): round-11 logic + T14 async-STAGE split.
// Round 11 showed VALU is NOT the bottleneck (6x VALU cut = same 71us);
// the cost is staging/compute serialization (HBM duty cycle ~55%).
// Now: issue tile t+1's 16 float4 loads into NAMED registers before the
// barriers, compute pass1/softmax/pass2 on tile t (~2500cy >> 900cy HBM
// latency), then barrier + convert/write regs->LDS. Register-destined
// global loads stay in flight across __syncthreads (T14 mechanism).
template <int NCHUNK_T>
__global__ __launch_bounds__(THREADS) void k1_accum(
    const float* __restrict__ x, const float* __restrict__ attn_w,
    const float* __restrict__ attn_b, float* __restrict__ ax_part,
    float* __restrict__ asum_part) {
  constexpr int RPC = T_ / NCHUNK_T;
  constexpr int TILES = RPC / TILE_R;

  const int blk = blockIdx.x;
  const int b = blk / NCHUNK_T;
  const int chunk = blk % NCHUNK_T;
  const int tid = threadIdx.x;
  const int wave = tid >> 6;
  const int lane = tid & 63;

  __shared__ __align__(16) __fp16 xt[TILE_R * XPITCH];  // 33.3 KB
  __shared__ __align__(16) __fp16 wt[K_ * XPITCH];      // 8.3 KB
  __shared__ float lg[TILE_R * LGPITCH];
  __shared__ __align__(16) float at[TILE_R * APITCH];

  // ---- stage W once (pre-scaled by log2e; logits feed only softmax)
  {
    const int k = tid >> 5;
    const int d0 = (tid & 31) * 16;
    const float4* wp = (const float4*)(attn_w + k * D_ + d0);
    const float4 g0 = wp[0], g1 = wp[1], g2 = wp[2], g3 = wp[3];
    h2* wdst = (h2*)(wt + k * XPITCH + d0);
    wdst[0] = pack2(g0.x * LOG2E, g0.y * LOG2E);
    wdst[1] = pack2(g0.z * LOG2E, g0.w * LOG2E);
    wdst[2] = pack2(g1.x * LOG2E, g1.y * LOG2E);
    wdst[3] = pack2(g1.z * LOG2E, g1.w * LOG2E);
    wdst[4] = pack2(g2.x * LOG2E, g2.y * LOG2E);
    wdst[5] = pack2(g2.z * LOG2E, g2.w * LOG2E);
    wdst[6] = pack2(g3.x * LOG2E, g3.y * LOG2E);
    wdst[7] = pack2(g3.z * LOG2E, g3.w * LOG2E);
  }

  const int r1 = lane & 31;
  const int myk = wave * 2 + (lane >> 5);
  const float mybias = attn_b[myk] * LOG2E;
  const int d0p2 = wave * 128 + lane * 2;

  v2f acc[K_];
#pragma unroll
  for (int k = 0; k < K_; ++k) acc[k] = (v2f){0.f, 0.f};
  v2f asum01 = {0.f, 0.f}, asum23 = {0.f, 0.f}, asum45 = {0.f, 0.f}, asum67 = {0.f, 0.f};

  const float* xbase = x + ((size_t)b * T_ + (size_t)chunk * RPC) * (size_t)D_;
  const int t4 = tid << 2;

  // 16 named staging registers (rule: no runtime-indexed arrays -> scratch)
  float4 f0, f1, f2, f3, f4, f5, f6, f7, f8, f9, f10, f11, f12, f13, f14, f15;

#define STAGE_LOAD(tt)                                                       \
  do {                                                                       \
    const float* src_ = xbase + (size_t)(tt) * TILE_R * D_ + t4;             \
    f0 = *(const float4*)(src_ + 0 * 1024);                                  \
    f1 = *(const float4*)(src_ + 1 * 1024);                                  \
    f2 = *(const float4*)(src_ + 2 * 1024);                                  \
    f3 = *(const float4*)(src_ + 3 * 1024);                                  \
    f4 = *(const float4*)(src_ + 4 * 1024);                                  \
    f5 = *(const float4*)(src_ + 5 * 1024);                                  \
    f6 = *(const float4*)(src_ + 6 * 1024);                                  \
    f7 = *(const float4*)(src_ + 7 * 1024);                                  \
    f8 = *(const float4*)(src_ + 8 * 1024);                                  \
    f9 = *(const float4*)(src_ + 9 * 1024);                                  \
    f10 = *(const float4*)(src_ + 10 * 1024);                                \
    f11 = *(const float4*)(src_ + 11 * 1024);                                \
    f12 = *(const float4*)(src_ + 12 * 1024);                                \
    f13 = *(const float4*)(src_ + 13 * 1024);                                \
    f14 = *(const float4*)(src_ + 14 * 1024);                                \
    f15 = *(const float4*)(src_ + 15 * 1024);                                \
  } while (0)

#define ST1(i, F)                                                            \
  do {                                                                       \
    const int g_ = (i)*1024 + t4;                                            \
    h2* dst_ = (h2*)(xt + (g_ >> 9) * XPITCH + (g_ & 511));                  \
    dst_[0] = pack2(F.x, F.y);                                               \
    dst_[1] = pack2(F.z, F.w);                                               \
  } while (0)

#define STAGE_WRITE()                                                        \
  do {                                                                       \
    ST1(0, f0); ST1(1, f1); ST1(2, f2); ST1(3, f3);                          \
    ST1(4, f4); ST1(5, f5); ST1(6, f6); ST1(7, f7);                          \
    ST1(8, f8); ST1(9, f9); ST1(10, f10); ST1(11, f11);                      \
    ST1(12, f12); ST1(13, f13); ST1(14, f14); ST1(15, f15);                  \
  } while (0)

  // prologue: stage tile 0
  STAGE_LOAD(0);
  STAGE_WRITE();

  for (int t = 0; t < TILES; ++t) {
    const bool pf = (t + 1 < TILES);
    if (pf) STAGE_LOAD(t + 1);  // issue early; in flight across barriers/compute
    __syncthreads();            // xt(t) visible (prologue or previous STAGE_WRITE)

    // ---- pass1: full 512-deep dot per (row, k) lane; 4 indep chains
    {
      float s0 = 0.f, s1 = 0.f, s2 = 0.f, s3 = 0.f;
      const h8* xr = (const h8*)(xt + r1 * XPITCH);
      const h8* wr = (const h8*)(wt + myk * XPITCH);
#pragma unroll 8
      for (int c = 0; c < 64; ++c) {
        const h8 xv = xr[c];
        const h8 wv = wr[c];
        s0 = fdot2((h2){xv[0], xv[1]}, (h2){wv[0], wv[1]}, s0);
        s1 = fdot2((h2){xv[2], xv[3]}, (h2){wv[2], wv[3]}, s1);
        s2 = fdot2((h2){xv[4], xv[5]}, (h2){wv[4], wv[5]}, s2);
        s3 = fdot2((h2){xv[6], xv[7]}, (h2){wv[6], wv[7]}, s3);
      }
      lg[r1 * LGPITCH + myk] = (s0 + s1) + (s2 + s3) + mybias;
    }
    __syncthreads();

    // ---- softmax: lane-per-row, lane-local (exp2 domain, no max-sub)
    if (wave == 0 && lane < 32) {
      const float* lr = lg + lane * LGPITCH;
      float e0 = dev_exp2(lr[0]), e1 = dev_exp2(lr[1]);
      float e2 = dev_exp2(lr[2]), e3 = dev_exp2(lr[3]);
      float e4 = dev_exp2(lr[4]), e5 = dev_exp2(lr[5]);
      float e6 = dev_exp2(lr[6]), e7 = dev_exp2(lr[7]);
      const float tot = ((e0 + e1) + (e2 + e3)) + ((e4 + e5) + (e6 + e7));
      const float inv = __builtin_amdgcn_rcpf(tot);
      float4* adst = (float4*)(at + lane * APITCH);
      adst[0] = (float4){e0 * inv, e1 * inv, e2 * inv, e3 * inv};
      adst[1] = (float4){e4 * inv, e5 * inv, e6 * inv, e7 * inv};
    }
    __syncthreads();

    // ---- pass2: acc[k] += a[r][k] * x[r][d-pair]; a reads broadcast
#pragma unroll 4
    for (int rr = 0; rr < TILE_R; ++rr) {
      const float4 alo = *(const float4*)(at + rr * APITCH);
      const float4 ahi = *(const float4*)(at + rr * APITCH + 4);
      const h2 xp = *(const h2*)(xt + rr * XPITCH + d0p2);
      const v2f xv = {(float)xp[0], (float)xp[1]};
      acc[0] += (v2f){alo.x, alo.x} * xv;
      acc[1] += (v2f){alo.y, alo.y} * xv;
      acc[2] += (v2f){alo.z, alo.z} * xv;
      acc[3] += (v2f){alo.w, alo.w} * xv;
      acc[4] += (v2f){ahi.x, ahi.x} * xv;
      acc[5] += (v2f){ahi.y, ahi.y} * xv;
      acc[6] += (v2f){ahi.z, ahi.z} * xv;
      acc[7] += (v2f){ahi.w, ahi.w} * xv;
      if (wave == 0) {
        asum01 += (v2f){alo.x, alo.y};
        asum23 += (v2f){alo.z, alo.w};
        asum45 += (v2f){ahi.x, ahi.y};
        asum67 += (v2f){ahi.z, ahi.w};
      }
    }

    if (pf) {
      __syncthreads();  // all waves done reading xt(t)
      STAGE_WRITE();    // vmcnt wait lands here, ~2500cy after issue
    }
  }
#undef STAGE_LOAD
#undef ST1
#undef STAGE_WRITE

  float* outp = ax_part + (size_t)blk * (K_ * D_);
#pragma unroll
  for (int k = 0; k < K_; ++k) *(v2f*)(outp + k * D_ + d0p2) = acc[k];
  if (tid == 0) {
    float* ap = asum_part + blk * K_;
    ap[0] = asum01.x; ap[1] = asum01.y; ap[2] = asum23.x; ap[3] = asum23.y;
    ap[4] = asum45.x; ap[5] = asum45.y; ap[6] = asum67.x; ap[7] = asum67.y;
  }
}

// k2a: 4 blocks per batch -> reduce chunks, subtract asum*centers, partial sq
template <int NCHUNK_T>
__global__ __launch_bounds__(256) void k2a(
    const float* __restrict__ ax_part, const float* __restrict__ asum_part,
    const float* __restrict__ centers, float* __restrict__ pbuf,
    float* __restrict__ sqpart) {
  const int b = blockIdx.x >> 2;
  const int q = blockIdx.x & 3;
  const int tid = threadIdx.x;
  __shared__ float s_as[K_];
  __shared__ float s_sq[4];
  if (tid < K_) {
    float s = 0.f;
    for (int c = 0; c < NCHUNK_T; ++c) s += asum_part[(b * NCHUNK_T + c) * K_ + tid];
    s_as[tid] = s;
  }
  __syncthreads();
  const int idx = q * 1024 + tid * 4;
  float4 s = {0.f, 0.f, 0.f, 0.f};
  const float* base = ax_part + (size_t)b * NCHUNK_T * (K_ * D_) + idx;
  for (int c = 0; c < NCHUNK_T; ++c) {
    const float4 v = *(const float4*)(base + (size_t)c * (K_ * D_));
    s.x += v.x; s.y += v.y; s.z += v.z; s.w += v.w;
  }
  const int k = idx >> 9;
  const float a = s_as[k];
  const float4 cv = *(const float4*)(centers + idx);
  float4 p;
  p.x = s.x - a * cv.x; p.y = s.y - a * cv.y;
  p.z = s.z - a * cv.z; p.w = s.w - a * cv.w;
  *(float4*)(pbuf + (size_t)b * (K_ * D_) + idx) = p;
  float sq = p.x * p.x + p.y * p.y + p.z * p.z + p.w * p.w;
#pragma unroll
  for (int m = 32; m; m >>= 1) sq += __shfl_xor(sq, m);
  if ((tid & 63) == 0) s_sq[tid >> 6] = sq;
  __syncthreads();
  if (tid == 0) sqpart[blockIdx.x] = (s_sq[0] + s_sq[1]) + (s_sq[2] + s_sq[3]);
}

// k2b: normalize (pbuf is L3-hot)
__global__ __launch_bounds__(1024) void k2b(const float* __restrict__ pbuf,
                                            const float* __restrict__ sqpart,
                                            float* __restrict__ out) {
  const int b = blockIdx.x;
  const float tot =
      (sqpart[b * 4] + sqpart[b * 4 + 1]) + (sqpart[b * 4 + 2] + sqpart[b * 4 + 3]);
  const float invn = 1.0f / fmaxf(__builtin_sqrtf(tot), 1e-12f);
  const int idx = threadIdx.x * 4;
  const float4 p = *(const float4*)(pbuf + (size_t)b * (K_ * D_) + idx);
  *(float4*)(out + (size_t)b * (K_ * D_) + idx) =
      (float4){p.x * invn, p.y * invn, p.z * invn, p.w * invn};
}

// legacy single-kernel finalize (smallest-workspace fallback)
template <int NCHUNK_T>
__global__ __launch_bounds__(1024) void k2_old(
    const float* __restrict__ ax_part, const float* __restrict__ asum_part,
    const float* __restrict__ centers, float* __restrict__ out) {
  const int b = blockIdx.x;
  const int tid = threadIdx.x;
  const int wave = tid >> 6;
  const int lane = tid & 63;
  __shared__ float s_asum[K_];
  __shared__ float s_sq[16];
  if (tid < K_) {
    float s = 0.f;
    for (int c = 0; c < NCHUNK_T; ++c) s += asum_part[(b * NCHUNK_T + c) * K_ + tid];
    s_asum[tid] = s;
  }
  __syncthreads();
  const int NPT = (K_ * D_) / 1024;
  float pooled[NPT];
  float sq = 0.f;
  const float* base = ax_part + (size_t)b * NCHUNK_T * (K_ * D_);
#pragma unroll
  for (int i = 0; i < NPT; ++i) {
    const int idx = tid + i * 1024;
    float v = 0.f;
    for (int c = 0; c < NCHUNK_T; ++c) v += base[(size_t)c * (K_ * D_) + idx];
    v -= s_asum[idx >> 9] * centers[idx];
    pooled[i] = v;
    sq = fmaf(v, v, sq);
  }
#pragma unroll
  for (int m = 32; m; m >>= 1) sq += __shfl_xor(sq, m);
  if (lane == 0) s_sq[wave] = sq;
  __syncthreads();
  float tot = 0.f;
#pragma unroll
  for (int wv = 0; wv < 16; ++wv) tot += s_sq[wv];
  const float invn = 1.0f / fmaxf(__builtin_sqrtf(tot), 1e-12f);
#pragma unroll
  for (int i = 0; i < NPT; ++i)
    out[(size_t)b * (K_ * D_) + tid + i * 1024] = pooled[i] * invn;
}

extern "C" void kernel_launch(void* const* d_in, const int* in_sizes, int n_in,
                              void* d_out, int out_size, void* d_ws, size_t ws_size,
                              hipStream_t stream) {
  (void)in_sizes; (void)n_in; (void)out_size;
  const float* x = (const float*)d_in[0];
  const float* centers = (const float*)d_in[1];
  const float* attn_w = (const float*)d_in[2];
  const float* attn_b = (const float*)d_in[3];
  float* out = (float*)d_out;

  const size_t KD = (size_t)K_ * D_;
  const size_t need16 = (size_t)B_ * 16 * KD * 4 + (size_t)B_ * 16 * K_ * 4 +
                        (size_t)B_ * KD * 4 + (size_t)B_ * 4 * 4;
  const size_t need8 = (size_t)B_ * 8 * KD * 4 + (size_t)B_ * 8 * K_ * 4 +
                       (size_t)B_ * KD * 4 + (size_t)B_ * 4 * 4;

  if (ws_size >= need16) {
    float* ax = (float*)d_ws;
    float* as = ax + (size_t)B_ * 16 * KD;
    float* pb = as + (size_t)B_ * 16 * K_;
    float* sp = pb + (size_t)B_ * KD;
    k1_accum<16><<<B_ * 16, THREADS, 0, stream>>>(x, attn_w, attn_b, ax, as);
    k2a<16><<<B_ * 4, 256, 0, stream>>>(ax, as, centers, pb, sp);
    k2b<<<B_, 1024, 0, stream>>>(pb, sp, out);
  } else if (ws_size >= need8) {
    float* ax = (float*)d_ws;
    float* as = ax + (size_t)B_ * 8 * KD;
    float* pb = as + (size_t)B_ * 8 * K_;
    float* sp = pb + (size_t)B_ * KD;
    k1_accum<8><<<B_ * 8, THREADS, 0, stream>>>(x, attn_w, attn_b, ax, as);
    k2a<8><<<B_ * 4, 256, 0, stream>>>(ax, as, centers, pb, sp);
    k2b<<<B_, 1024, 0, stream>>>(pb, sp, out);
  } else {
    float* ax = (float*)d_ws;
    float* as = ax + (size_t)B_ * 8 * KD;
    k1_accum<8><<<B_ * 8, THREADS, 0, stream>>>(x, attn_w, attn_b, ax, as);
    k2_old<8><<<B_, 1024, 0, stream>>>(ax, as, centers, out);
  }
}